// Round 2
// baseline (410.057 us; speedup 1.0000x reference)
//
#include <hip/hip_runtime.h>

#define BATCH 64
#define SEQ 729
#define DIM 64
#define NT 12      // ceil(729/64)
#define STR 72     // LDS row stride in bf16 elems (2-way conflicts only = free)

typedef __attribute__((ext_vector_type(8))) short bf16x8;
typedef __attribute__((ext_vector_type(4))) float f32x4;

__device__ __forceinline__ unsigned short f2bf(float f) {
    unsigned int u = __float_as_uint(f);
    u += 0x7fffu + ((u >> 16) & 1u);   // round-to-nearest-even
    return (unsigned short)(u >> 16);
}

// tanh(x) = 1 - 2/(exp2(2x*log2e)+1)
__device__ __forceinline__ float fast_tanh(float x) {
    float e = __builtin_amdgcn_exp2f(x * 2.88539008177792681f);
    return 1.0f - 2.0f * __builtin_amdgcn_rcpf(e + 1.0f);
}

__global__ __launch_bounds__(256, 3) void attn_kernel(
    const float* __restrict__ Qg, const float* __restrict__ Kg,
    const float* __restrict__ Vg, const int* __restrict__ Mg,
    float* __restrict__ Og, float* __restrict__ Ag)
{
    // Double-buffered K/V; Qs reused as Ps after Q-fragments are hoisted.
    __shared__ unsigned short Ks[2][64 * STR];
    __shared__ unsigned short Vs[2][64 * STR];
    __shared__ unsigned short Qs[64 * STR];   // later: Ps (wave-private rows)

    const int tid = threadIdx.x;
    const int q0  = blockIdx.x * 64;
    const int b   = blockIdx.y;

    const float* Qb = Qg + (size_t)b * SEQ * DIM;
    const float* Kb = Kg + (size_t)b * SEQ * DIM;
    const float* Vb = Vg + (size_t)b * SEQ * DIM;
    const int*   Mb = Mg + (size_t)b * SEQ * SEQ;
    float* Ob = Og + (size_t)b * SEQ * DIM;
    float* Ab = Ag + (size_t)b * SEQ * SEQ;

    const int w    = tid >> 6;
    const int lane = tid & 63;
    const int quad = lane >> 4;
    const int l15  = lane & 15;
    const int qrow = w * 16;

    // --- staging-register geometry ---
    const int rA  = tid >> 3;          // K rows rA and rA+32
    const int cK  = (tid & 7) * 8;     // K col base (8 floats)
    const int vd0 = (tid & 15) * 4;    // V: 4 dims
    const int vk0 = (tid >> 4) * 4;    // V: 4 k-rows

    float4 kr[4];                      // K tile regs: (rA,c..c+3),(rA,c+4..7),(rA+32,...)
    float4 vr[4];                      // V tile regs: rows vk0..vk0+3, cols vd0..vd0+3
    int    mcur[16], mnext[16];        // mask regs [nt2*4+r]

    auto load_kv = [&](int k0n) {
        int g1 = k0n + rA, g2 = k0n + rA + 32;
        if (g1 < SEQ) {
            kr[0] = *(const float4*)(Kb + g1 * DIM + cK);
            kr[1] = *(const float4*)(Kb + g1 * DIM + cK + 4);
        } else { kr[0] = float4{0,0,0,0}; kr[1] = float4{0,0,0,0}; }
        if (g2 < SEQ) {
            kr[2] = *(const float4*)(Kb + g2 * DIM + cK);
            kr[3] = *(const float4*)(Kb + g2 * DIM + cK + 4);
        } else { kr[2] = float4{0,0,0,0}; kr[3] = float4{0,0,0,0}; }
        #pragma unroll
        for (int i = 0; i < 4; ++i) {
            int gk = k0n + vk0 + i;
            if (gk < SEQ) vr[i] = *(const float4*)(Vb + gk * DIM + vd0);
            else          vr[i] = float4{0,0,0,0};
        }
    };
    auto load_mask = [&](int k0n, int* dst) {
        #pragma unroll
        for (int nt2 = 0; nt2 < 4; ++nt2) {
            int gk = k0n + nt2 * 16 + l15;
            #pragma unroll
            for (int r = 0; r < 4; ++r) {
                int gq = q0 + qrow + quad * 4 + r;
                dst[nt2 * 4 + r] = (gq < SEQ && gk < SEQ)
                    ? __builtin_nontemporal_load(Mb + gq * SEQ + gk) : 0;
            }
        }
    };
    auto store_kv = [&](int buf) {
        union { unsigned short u[8]; bf16x8 v; } t;
        t.u[0]=f2bf(kr[0].x); t.u[1]=f2bf(kr[0].y); t.u[2]=f2bf(kr[0].z); t.u[3]=f2bf(kr[0].w);
        t.u[4]=f2bf(kr[1].x); t.u[5]=f2bf(kr[1].y); t.u[6]=f2bf(kr[1].z); t.u[7]=f2bf(kr[1].w);
        *(bf16x8*)&Ks[buf][rA * STR + cK] = t.v;
        t.u[0]=f2bf(kr[2].x); t.u[1]=f2bf(kr[2].y); t.u[2]=f2bf(kr[2].z); t.u[3]=f2bf(kr[2].w);
        t.u[4]=f2bf(kr[3].x); t.u[5]=f2bf(kr[3].y); t.u[6]=f2bf(kr[3].z); t.u[7]=f2bf(kr[3].w);
        *(bf16x8*)&Ks[buf][(rA + 32) * STR + cK] = t.v;
        #pragma unroll
        for (int j = 0; j < 4; ++j) {
            float vj[4] = { j==0?vr[0].x:j==1?vr[0].y:j==2?vr[0].z:vr[0].w,
                            j==0?vr[1].x:j==1?vr[1].y:j==2?vr[1].z:vr[1].w,
                            j==0?vr[2].x:j==1?vr[2].y:j==2?vr[2].z:vr[2].w,
                            j==0?vr[3].x:j==1?vr[3].y:j==2?vr[3].z:vr[3].w };
            unsigned long long pk =
                  (unsigned long long)f2bf(vj[0])
                | ((unsigned long long)f2bf(vj[1]) << 16)
                | ((unsigned long long)f2bf(vj[2]) << 32)
                | ((unsigned long long)f2bf(vj[3]) << 48);
            *(unsigned long long*)&Vs[buf][(vd0 + j) * STR + vk0] = pk;
        }
    };

    // ---- preload tile 0 (K/V/mask) into regs; stage Q tile ----
    load_kv(0);
    load_mask(0, mcur);

    #pragma unroll
    for (int it = 0; it < 2; ++it) {
        int idx = tid + it * 256;
        int r = idx >> 3;
        int c = (idx & 7) * 8;
        int gq = q0 + r;
        union { unsigned short u[8]; bf16x8 v; } t;
        if (gq < SEQ) {
            const float* src = Qb + gq * DIM + c;
            float4 x0 = *(const float4*)src;
            float4 x1 = *(const float4*)(src + 4);
            t.u[0]=f2bf(x0.x); t.u[1]=f2bf(x0.y); t.u[2]=f2bf(x0.z); t.u[3]=f2bf(x0.w);
            t.u[4]=f2bf(x1.x); t.u[5]=f2bf(x1.y); t.u[6]=f2bf(x1.z); t.u[7]=f2bf(x1.w);
        } else {
            #pragma unroll
            for (int j = 0; j < 8; ++j) t.u[j] = 0;
        }
        *(bf16x8*)&Qs[r * STR + c] = t.v;
    }
    __syncthreads();

    // Q fragments are loop-invariant: hoist, then Qs becomes Ps.
    const bf16x8 aq0 = *(const bf16x8*)&Qs[(qrow + l15) * STR + quad * 8];
    const bf16x8 aq1 = *(const bf16x8*)&Qs[(qrow + l15) * STR + 32 + quad * 8];

    f32x4 oacc[4];
    #pragma unroll
    for (int dt = 0; dt < 4; ++dt) {
        oacc[dt][0]=0.f; oacc[dt][1]=0.f; oacc[dt][2]=0.f; oacc[dt][3]=0.f;
    }

    for (int kt = 0; kt < NT; ++kt) {
        const int k0  = kt * 64;
        const int cur = kt & 1;

        // ---- drain staged regs (tile kt) into LDS[cur] ----
        store_kv(cur);
        __syncthreads();

        // ---- issue prefetch for tile kt+1 (lands during compute below) ----
        if (kt + 1 < NT) {
            load_kv(k0 + 64);
            load_mask(k0 + 64, mnext);
        }

        // ---- QK^T ----
        f32x4 sacc[4];
        #pragma unroll
        for (int nt2 = 0; nt2 < 4; ++nt2) {
            bf16x8 bk0 = *(const bf16x8*)&Ks[cur][(nt2 * 16 + l15) * STR + quad * 8];
            bf16x8 bk1 = *(const bf16x8*)&Ks[cur][(nt2 * 16 + l15) * STR + 32 + quad * 8];
            f32x4 c; c[0]=0.f; c[1]=0.f; c[2]=0.f; c[3]=0.f;
            c = __builtin_amdgcn_mfma_f32_16x16x32_bf16(aq0, bk0, c, 0, 0, 0);
            c = __builtin_amdgcn_mfma_f32_16x16x32_bf16(aq1, bk1, c, 0, 0, 0);
            sacc[nt2] = c;
        }

        // ---- scale, mask, tanh, zero-diag; store attention; write Ps (=Qs) ----
        #pragma unroll
        for (int nt2 = 0; nt2 < 4; ++nt2) {
            int gk = k0 + nt2 * 16 + l15;
            #pragma unroll
            for (int r = 0; r < 4; ++r) {
                int qloc = qrow + quad * 4 + r;
                int gq = q0 + qloc;
                float sv = sacc[nt2][r] * 0.125f;     // 1/sqrt(64)
                bool msk = (mcur[nt2 * 4 + r] == 0);
                float x = msk ? -1e9f : sv;
                float p = fast_tanh(x);
                if (msk) p = -1.0f;
                if (gq == gk) p = 0.0f;               // ignore_diag
                bool inb = (gq < SEQ) && (gk < SEQ);
                if (!inb) p = 0.0f;
                if (inb) __builtin_nontemporal_store(p, Ab + gq * SEQ + gk);
                Qs[qloc * STR + nt2 * 16 + l15] = f2bf(p);
            }
        }
        // Ps rows are wave-private -> no barrier before PV.

        // ---- PV ----
        const bf16x8 ap0 = *(const bf16x8*)&Qs[(qrow + l15) * STR + quad * 8];
        const bf16x8 ap1 = *(const bf16x8*)&Qs[(qrow + l15) * STR + 32 + quad * 8];
        #pragma unroll
        for (int dt = 0; dt < 4; ++dt) {
            bf16x8 bv0 = *(const bf16x8*)&Vs[cur][(dt * 16 + l15) * STR + quad * 8];
            bf16x8 bv1 = *(const bf16x8*)&Vs[cur][(dt * 16 + l15) * STR + 32 + quad * 8];
            oacc[dt] = __builtin_amdgcn_mfma_f32_16x16x32_bf16(ap0, bv0, oacc[dt], 0, 0, 0);
            oacc[dt] = __builtin_amdgcn_mfma_f32_16x16x32_bf16(ap1, bv1, oacc[dt], 0, 0, 0);
        }

        // rotate mask regs
        #pragma unroll
        for (int i = 0; i < 16; ++i) mcur[i] = mnext[i];
    }

    // ---- epilogue: out[q][d] ----
    #pragma unroll
    for (int dt = 0; dt < 4; ++dt) {
        #pragma unroll
        for (int r = 0; r < 4; ++r) {
            int gq = q0 + qrow + quad * 4 + r;
            if (gq < SEQ) Ob[gq * DIM + dt * 16 + l15] = oacc[dt][r];
        }
    }
}

extern "C" void kernel_launch(void* const* d_in, const int* in_sizes, int n_in,
                              void* d_out, int out_size, void* d_ws, size_t ws_size,
                              hipStream_t stream) {
    const float* Q = (const float*)d_in[0];
    const float* K = (const float*)d_in[1];
    const float* V = (const float*)d_in[2];
    const int*   M = (const int*)d_in[3];
    float* Out  = (float*)d_out;
    float* Attn = Out + (size_t)BATCH * SEQ * DIM;   // tuple order: (out, attention)
    dim3 grid(NT, BATCH);
    attn_kernel<<<grid, 256, 0, stream>>>(Q, K, V, M, Out, Attn);
}

// Round 3
// 326.742 us; speedup vs baseline: 1.2550x; 1.2550x over previous
//
#include <hip/hip_runtime.h>

#define BATCH 64
#define SEQ 729
#define DIM 64
#define NT 12      // ceil(729/64)
#define STRB 72    // bf16 LDS row stride (Ks/Vs/Qs)
#define STRW 68    // dword LDS row stride (mask/P fp32 tile): 16B-aligned rows

typedef __attribute__((ext_vector_type(8))) short bf16x8;
typedef __attribute__((ext_vector_type(4))) float f32x4;
// 4B-aligned vector views for the 729-strided global rows (gfx950 supports
// unaligned global dwordx4; rows are only dword-aligned since 729*4 % 16 != 0)
typedef int   i32x4a __attribute__((ext_vector_type(4), aligned(4)));
typedef float f32x4a __attribute__((ext_vector_type(4), aligned(4)));

__device__ __forceinline__ unsigned short f2bf(float f) {
    unsigned int u = __float_as_uint(f);
    u += 0x7fffu + ((u >> 16) & 1u);   // round-to-nearest-even
    return (unsigned short)(u >> 16);
}

__device__ __forceinline__ unsigned long long pack4bf(float a, float b, float c, float d) {
    return (unsigned long long)f2bf(a)
         | ((unsigned long long)f2bf(b) << 16)
         | ((unsigned long long)f2bf(c) << 32)
         | ((unsigned long long)f2bf(d) << 48);
}

// tanh(x) = 1 - 2/(exp2(2x*log2e)+1)
__device__ __forceinline__ float fast_tanh(float x) {
    float e = __builtin_amdgcn_exp2f(x * 2.88539008177792681f);
    return 1.0f - 2.0f * __builtin_amdgcn_rcpf(e + 1.0f);
}

__global__ __launch_bounds__(256, 3) void attn_kernel(
    const float* __restrict__ Qg, const float* __restrict__ Kg,
    const float* __restrict__ Vg, const int* __restrict__ Mg,
    float* __restrict__ Og, float* __restrict__ Ag)
{
    __shared__ unsigned short Ks[64 * STRB];  // [k][d] bf16
    __shared__ unsigned short Vs[64 * STRB];  // [d][k] bf16 (transposed)
    __shared__ unsigned short Qs[64 * STRB];  // Q bf16, then P bf16 (wave-private rows)
    __shared__ float Pf[64 * STRW];           // mask int, then P fp32 (wave-private rows)
    int* Mint = (int*)Pf;

    const int tid = threadIdx.x;
    const int q0  = blockIdx.x * 64;
    const int b   = blockIdx.y;

    const float* Qb = Qg + (size_t)b * SEQ * DIM;
    const float* Kb = Kg + (size_t)b * SEQ * DIM;
    const float* Vb = Vg + (size_t)b * SEQ * DIM;
    const int*   Mb = Mg + (size_t)b * SEQ * SEQ;
    float* Ob = Og + (size_t)b * SEQ * DIM;
    float* Ab = Ag + (size_t)b * SEQ * SEQ;

    const int lane = tid & 63;
    const int quad = lane >> 4;
    const int l15  = lane & 15;
    const int qrow = (tid >> 6) * 16;      // wave's q-strip base (local)

    // block-cooperative staging geometry: 16 consecutive threads cover one
    // row's 64 cols -> 256B contiguous segments, float4 per lane
    const int rr = tid >> 4;               // row group 0..15 (+16*i)
    const int cc = (tid & 15) * 4;         // col (floats)
    // V staging (row-2 scheme, already 256B-coalesced)
    const int vd0 = (tid & 15) * 4;        // dims
    const int vk0 = (tid >> 4) * 4;        // k rows
    // wave-private mask/P row-major geometry: 16 lanes cover one row's 64 cols
    const int prow = qrow + (lane >> 4);   // + 4*i -> rows qrow..qrow+15
    const int pcol = (lane & 15) * 4;

    float4 kr[4], vr[4];
    i32x4a mr[4];

    auto load_k = [&](int k0n) {
        #pragma unroll
        for (int i = 0; i < 4; ++i) {
            int gk = k0n + rr + 16 * i;
            kr[i] = (gk < SEQ) ? *(const float4*)(Kb + gk * DIM + cc)
                               : float4{0, 0, 0, 0};
        }
    };
    auto load_v = [&](int k0n) {
        #pragma unroll
        for (int i = 0; i < 4; ++i) {
            int gk = k0n + vk0 + i;
            vr[i] = (gk < SEQ) ? *(const float4*)(Vb + gk * DIM + vd0)
                               : float4{0, 0, 0, 0};
        }
    };
    auto load_mask = [&](int k0n) {
        #pragma unroll
        for (int i = 0; i < 4; ++i) {
            int gq = q0 + prow + 4 * i;
            int gk = k0n + pcol;
            if (gq < SEQ && gk + 3 < SEQ) {
                mr[i] = *(const i32x4a*)(Mb + (size_t)gq * SEQ + gk);
            } else if (gq < SEQ) {
                i32x4a t;
                #pragma unroll
                for (int e = 0; e < 4; ++e)
                    t[e] = (gk + e < SEQ) ? Mb[(size_t)gq * SEQ + gk + e] : 0;
                mr[i] = t;
            } else {
                mr[i] = i32x4a{0, 0, 0, 0};
            }
        }
    };
    auto drain_mask = [&]() {   // wave-private rows -> no barrier needed
        #pragma unroll
        for (int i = 0; i < 4; ++i)
            *(i32x4a*)&Mint[(prow + 4 * i) * STRW + pcol] = mr[i];
    };
    auto drain_kv = [&]() {
        #pragma unroll
        for (int i = 0; i < 4; ++i)
            *(unsigned long long*)&Ks[(rr + 16 * i) * STRB + cc] =
                pack4bf(kr[i].x, kr[i].y, kr[i].z, kr[i].w);
        #pragma unroll
        for (int j = 0; j < 4; ++j) {
            float v0 = j==0?vr[0].x:j==1?vr[0].y:j==2?vr[0].z:vr[0].w;
            float v1 = j==0?vr[1].x:j==1?vr[1].y:j==2?vr[1].z:vr[1].w;
            float v2 = j==0?vr[2].x:j==1?vr[2].y:j==2?vr[2].z:vr[2].w;
            float v3 = j==0?vr[3].x:j==1?vr[3].y:j==2?vr[3].z:vr[3].w;
            *(unsigned long long*)&Vs[(vd0 + j) * STRB + vk0] = pack4bf(v0, v1, v2, v3);
        }
    };

    // ---- stage Q tile (256B-coalesced float4 loads) ----
    #pragma unroll
    for (int i = 0; i < 4; ++i) {
        int gq = q0 + rr + 16 * i;
        float4 x = (gq < SEQ) ? *(const float4*)(Qb + gq * DIM + cc)
                              : float4{0, 0, 0, 0};
        *(unsigned long long*)&Qs[(rr + 16 * i) * STRB + cc] = pack4bf(x.x, x.y, x.z, x.w);
    }
    __syncthreads();

    // hoist loop-invariant Q fragments; Qs becomes the P bf16 buffer
    const bf16x8 aq0 = *(const bf16x8*)&Qs[(qrow + l15) * STRB + quad * 8];
    const bf16x8 aq1 = *(const bf16x8*)&Qs[(qrow + l15) * STRB + 32 + quad * 8];

    // preload tile 0 into regs
    load_k(0); load_v(0); load_mask(0);

    f32x4 oacc[4];
    #pragma unroll
    for (int dt = 0; dt < 4; ++dt) {
        oacc[dt][0]=0.f; oacc[dt][1]=0.f; oacc[dt][2]=0.f; oacc[dt][3]=0.f;
    }

    for (int kt = 0; kt < NT; ++kt) {
        const int k0 = kt * 64;

        __syncthreads();            // prev tile's Ks/Vs readers done
        drain_mask();               // regs (tile kt) -> LDS
        drain_kv();
        __syncthreads();            // staging visible

        // prefetch tile kt+1 into regs (lands during compute below)
        if (kt + 1 < NT) {
            load_k(k0 + 64); load_v(k0 + 64); load_mask(k0 + 64);
        }

        // ---- QK^T ----
        f32x4 sacc[4];
        #pragma unroll
        for (int nt2 = 0; nt2 < 4; ++nt2) {
            bf16x8 bk0 = *(const bf16x8*)&Ks[(nt2 * 16 + l15) * STRB + quad * 8];
            bf16x8 bk1 = *(const bf16x8*)&Ks[(nt2 * 16 + l15) * STRB + 32 + quad * 8];
            f32x4 c; c[0]=0.f; c[1]=0.f; c[2]=0.f; c[3]=0.f;
            c = __builtin_amdgcn_mfma_f32_16x16x32_bf16(aq0, bk0, c, 0, 0, 0);
            c = __builtin_amdgcn_mfma_f32_16x16x32_bf16(aq1, bk1, c, 0, 0, 0);
            sacc[nt2] = c;
        }

        // ---- scale, mask (from LDS), tanh, zero-diag; write P fp32+bf16 ----
        #pragma unroll
        for (int nt2 = 0; nt2 < 4; ++nt2) {
            int col = nt2 * 16 + l15;
            int gk  = k0 + col;
            #pragma unroll
            for (int r = 0; r < 4; ++r) {
                int qloc = qrow + quad * 4 + r;
                int gq = q0 + qloc;
                int m = Mint[qloc * STRW + col];
                float sv = sacc[nt2][r] * 0.125f;       // 1/sqrt(64)
                bool msk = (m == 0);
                float p = fast_tanh(msk ? -1e9f : sv);
                if (msk) p = -1.0f;
                if (gq == gk) p = 0.0f;                 // ignore_diag
                if (gq >= SEQ || gk >= SEQ) p = 0.0f;   // padding
                Pf[qloc * STRW + col] = p;              // in-place over mask
                Qs[qloc * STRB + col] = f2bf(p);
            }
        }

        // ---- attention write-out: wave-private rows, row-contiguous float4 ----
        #pragma unroll
        for (int i = 0; i < 4; ++i) {
            int row = prow + 4 * i;
            int gq  = q0 + row;
            int gk  = k0 + pcol;
            f32x4 pv = *(const f32x4*)&Pf[row * STRW + pcol];
            if (gq < SEQ) {
                if (gk + 3 < SEQ) {
                    *(f32x4a*)(Ab + (size_t)gq * SEQ + gk) = pv;
                } else {
                    #pragma unroll
                    for (int e = 0; e < 4; ++e)
                        if (gk + e < SEQ) Ab[(size_t)gq * SEQ + gk + e] = pv[e];
                }
            }
        }

        // ---- PV ----
        const bf16x8 ap0 = *(const bf16x8*)&Qs[(qrow + l15) * STRB + quad * 8];
        const bf16x8 ap1 = *(const bf16x8*)&Qs[(qrow + l15) * STRB + 32 + quad * 8];
        #pragma unroll
        for (int dt = 0; dt < 4; ++dt) {
            bf16x8 bv0 = *(const bf16x8*)&Vs[(dt * 16 + l15) * STRB + quad * 8];
            bf16x8 bv1 = *(const bf16x8*)&Vs[(dt * 16 + l15) * STRB + 32 + quad * 8];
            oacc[dt] = __builtin_amdgcn_mfma_f32_16x16x32_bf16(ap0, bv0, oacc[dt], 0, 0, 0);
            oacc[dt] = __builtin_amdgcn_mfma_f32_16x16x32_bf16(ap1, bv1, oacc[dt], 0, 0, 0);
        }
    }

    // ---- epilogue: stage out tile in Pf (wave-private), write float4 ----
    #pragma unroll
    for (int dt = 0; dt < 4; ++dt)
        #pragma unroll
        for (int r = 0; r < 4; ++r)
            Pf[(qrow + quad * 4 + r) * STRW + dt * 16 + l15] = oacc[dt][r];
    #pragma unroll
    for (int i = 0; i < 4; ++i) {
        int row = prow + 4 * i;
        int gq  = q0 + row;
        f32x4 ov = *(const f32x4*)&Pf[row * STRW + pcol];
        if (gq < SEQ) *(f32x4*)(Ob + (size_t)gq * DIM + pcol) = ov;  // 16B-aligned
    }
}

extern "C" void kernel_launch(void* const* d_in, const int* in_sizes, int n_in,
                              void* d_out, int out_size, void* d_ws, size_t ws_size,
                              hipStream_t stream) {
    const float* Q = (const float*)d_in[0];
    const float* K = (const float*)d_in[1];
    const float* V = (const float*)d_in[2];
    const int*   M = (const int*)d_in[3];
    float* Out  = (float*)d_out;
    float* Attn = Out + (size_t)BATCH * SEQ * DIM;   // tuple order: (out, attention)
    dim3 grid(NT, BATCH);
    attn_kernel<<<grid, 256, 0, stream>>>(Q, K, V, M, Out, Attn);
}